// Round 23
// baseline (447.471 us; speedup 1.0000x reference)
//
#include <hip/hip_runtime.h>
#include <math.h>

#define B_    2
#define S_    4096
#define D_    1024
#define H_    16
#define DH_   64
#define NH_   4
#define BSD_  8388608     // B*S*D
#define SCALE_ 0.125f     // DH^-0.5

typedef __attribute__((ext_vector_type(8))) short   bf16x8;   // 8 bf16 (4 VGPR)
typedef __attribute__((ext_vector_type(4))) float   f32x4;
typedef __attribute__((ext_vector_type(8))) unsigned short ushort8;
typedef __attribute__((ext_vector_type(4))) unsigned short ushort4v;

__device__ __forceinline__ float sigf(float x) { return 1.f / (1.f + expf(-x)); }

__device__ __forceinline__ unsigned short f2bf(float f) {   // RNE float->bf16 bits
    union { float f; unsigned u; } v; v.f = f;
    unsigned r = v.u + 0x7FFF + ((v.u >> 16) & 1);
    return (unsigned short)(r >> 16);
}
__device__ __forceinline__ float bf2f(unsigned short u) {
    union { unsigned u; float f; } v; v.u = ((unsigned)u) << 16; return v.f;
}

__device__ __forceinline__ void gload_lds16(const void* g, void* l) {
    __builtin_amdgcn_global_load_lds(
        (const __attribute__((address_space(1))) void*)(g),
        (__attribute__((address_space(3))) void*)(l),
        16, 0, 0);
}

// XCD-chunked 1D-grid remap for M=8192,N=1024 GEMMs (512 blocks):
// each XCD (bid%8) owns 64 consecutive logical tiles = 8 A-row-panels x all x.
__device__ __forceinline__ void gemm_tile_remap(int bid, int& m0, int& n0) {
    int logical = (bid & 7) * 64 + (bid >> 3);
    m0 = (logical >> 3) * 128;
    n0 = (logical & 7) * 128;
}

// ---------------------------------------------------------------------------
// Split-precision qk GEMM (RNE hi/lo, 3 MFMA) -- A pre-split (R22-validated),
// pure global_load_lds staging; XCD-chunked grid (bit-identical remap).
// ---------------------------------------------------------------------------
__global__ __launch_bounds__(256)
void gemm_qk_split(const unsigned short* __restrict__ Ahg,
                   const unsigned short* __restrict__ Alg,
                   const unsigned short* __restrict__ BTh,
                   const unsigned short* __restrict__ BTl,
                   float* __restrict__ out) {
    __shared__ __align__(16) unsigned short Ah[128 * 32];
    __shared__ __align__(16) unsigned short Al[128 * 32];
    __shared__ __align__(16) unsigned short Bh[128 * 32];
    __shared__ __align__(16) unsigned short Bl[128 * 32];
    const int tid = threadIdx.x;
    const int lane = tid & 63, w = tid >> 6;
    const int wr = w >> 1, wc = w & 1;
    int m0, n0;
    gemm_tile_remap(blockIdx.x, m0, n0);
    const int l15 = lane & 15, lq = lane >> 4;

    f32x4 acc[4][4];
#pragma unroll
    for (int i = 0; i < 4; ++i)
#pragma unroll
        for (int j = 0; j < 4; ++j) acc[i][j] = (f32x4)0.f;

    for (int kt = 0; kt < 1024; kt += 32) {
#pragma unroll
        for (int i = 0; i < 2; ++i) {
            int d = i * 256 + tid;               // 16B chunk 0..511
            int r = d >> 2, sl = d & 3;
            size_t ga = (size_t)(m0 + r) * 1024 + kt + sl * 8;
            size_t gb = (size_t)(n0 + r) * 1024 + kt + sl * 8;
            gload_lds16(&Ahg[ga], &Ah[(size_t)d * 8]);
            gload_lds16(&Alg[ga], &Al[(size_t)d * 8]);
            gload_lds16(&BTh[gb], &Bh[(size_t)d * 8]);
            gload_lds16(&BTl[gb], &Bl[(size_t)d * 8]);
        }
        __syncthreads();
        bf16x8 afh[4], afl[4], bfh[4], bfl[4];
#pragma unroll
        for (int f = 0; f < 4; ++f) {
            int ar = (wr * 64 + f * 16 + l15) * 32 + lq * 8;
            int br = (wc * 64 + f * 16 + l15) * 32 + lq * 8;
            afh[f] = *reinterpret_cast<const bf16x8*>(&Ah[ar]);
            afl[f] = *reinterpret_cast<const bf16x8*>(&Al[ar]);
            bfh[f] = *reinterpret_cast<const bf16x8*>(&Bh[br]);
            bfl[f] = *reinterpret_cast<const bf16x8*>(&Bl[br]);
        }
#pragma unroll
        for (int fm = 0; fm < 4; ++fm)
#pragma unroll
            for (int fn = 0; fn < 4; ++fn) {
                acc[fm][fn] = __builtin_amdgcn_mfma_f32_16x16x32_bf16(afh[fm], bfh[fn], acc[fm][fn], 0, 0, 0);
                acc[fm][fn] = __builtin_amdgcn_mfma_f32_16x16x32_bf16(afh[fm], bfl[fn], acc[fm][fn], 0, 0, 0);
                acc[fm][fn] = __builtin_amdgcn_mfma_f32_16x16x32_bf16(afl[fm], bfh[fn], acc[fm][fn], 0, 0, 0);
            }
        __syncthreads();
    }

#pragma unroll
    for (int fn = 0; fn < 4; ++fn) {
        int n = n0 + wc * 64 + fn * 16 + l15;
        int h = n >> 6, dh = n & 63;
#pragma unroll
        for (int fm = 0; fm < 4; ++fm) {
#pragma unroll
            for (int q = 0; q < 4; ++q) {
                int m = m0 + wr * 64 + fm * 16 + lq * 4 + q;
                int bb = m >> 12, s = m & 4095;
                out[((((size_t)bb * H_ + h) * S_ + s) << 6) + dh] = acc[fm][fn][q];
            }
        }
    }
}

// ---------------------------------------------------------------------------
// bf16 MFMA GEMM, 128x128 tile, BK=64, XOR-swizzled LDS; XCD-chunked grid.
// MODE 0: out bf16 head-layout                       (v = x2 @ Wv)
// MODE 1: out fp32 = resid + sigf(gate[n]) * acc     (y1)
// MODE 2: out bf16 = relu(acc + bias[n])             (t)
// MODE 3: out fp32 = resid + sigf(gate[n])*(acc+bias)(y2)
// ---------------------------------------------------------------------------
template<int MODE>
__global__ __launch_bounds__(256)
void gemm_bf16(const unsigned short* __restrict__ A,
               const unsigned short* __restrict__ BT,
               void* __restrict__ outv,
               const float* __restrict__ bias,
               const float* __restrict__ resid,
               const float* __restrict__ gatev) {
    __shared__ __align__(16) unsigned short Als[128 * 64];
    __shared__ __align__(16) unsigned short Bls[128 * 64];
    const int tid = threadIdx.x;
    const int lane = tid & 63, w = tid >> 6;
    const int wr = w >> 1, wc = w & 1;
    int m0, n0;
    gemm_tile_remap(blockIdx.x, m0, n0);
    const int l15 = lane & 15, l4 = lane >> 4;

    f32x4 acc[4][4];
#pragma unroll
    for (int i = 0; i < 4; ++i)
#pragma unroll
        for (int j = 0; j < 4; ++j) acc[i][j] = (f32x4)0.f;

    for (int kt = 0; kt < 1024; kt += 64) {
#pragma unroll
        for (int i = 0; i < 4; ++i) {
            int d = i * 256 + tid;               // 16B chunk 0..1023
            int r = d >> 3, sl = d & 7;
            int ssl = sl ^ (r & 7);              // pre-swizzled source slot
            gload_lds16(&A [(size_t)(m0 + r) * 1024 + kt + ssl * 8], &Als[(size_t)d * 8]);
            gload_lds16(&BT[(size_t)(n0 + r) * 1024 + kt + ssl * 8], &Bls[(size_t)d * 8]);
        }
        __syncthreads();
#pragma unroll
        for (int ks = 0; ks < 2; ++ks) {
            bf16x8 af[4], bfr[4];
#pragma unroll
            for (int f = 0; f < 4; ++f) {
                int ra = wr * 64 + f * 16 + l15;
                int rb = wc * 64 + f * 16 + l15;
                int sa = (ks * 4 + l4) ^ (ra & 7);
                int sb = (ks * 4 + l4) ^ (rb & 7);
                af[f]  = *reinterpret_cast<const bf16x8*>(&Als[(size_t)ra * 64 + sa * 8]);
                bfr[f] = *reinterpret_cast<const bf16x8*>(&Bls[(size_t)rb * 64 + sb * 8]);
            }
#pragma unroll
            for (int fm = 0; fm < 4; ++fm)
#pragma unroll
                for (int fn = 0; fn < 4; ++fn)
                    acc[fm][fn] = __builtin_amdgcn_mfma_f32_16x16x32_bf16(af[fm], bfr[fn], acc[fm][fn], 0, 0, 0);
        }
        __syncthreads();
    }

#pragma unroll
    for (int fn = 0; fn < 4; ++fn) {
        int n = n0 + wc * 64 + fn * 16 + l15;
        float sg = 0.f, bs = 0.f;
        if (MODE == 1) sg = sigf(gatev[n]);
        if (MODE == 2) bs = bias[n];
        if (MODE == 3) { sg = sigf(gatev[n]); bs = bias[n]; }
#pragma unroll
        for (int fm = 0; fm < 4; ++fm) {
#pragma unroll
            for (int q = 0; q < 4; ++q) {
                int m = m0 + wr * 64 + fm * 16 + l4 * 4 + q;
                float v = acc[fm][fn][q];
                if (MODE == 0) {
                    int bb = m >> 12, s = m & 4095;
                    int h = n >> 6, dh = n & 63;
                    ((unsigned short*)outv)[((((size_t)bb * H_ + h) * S_ + s) << 6) + dh] = f2bf(v);
                } else if (MODE == 1) {
                    size_t idx = (size_t)m * 1024 + n;
                    ((float*)outv)[idx] = resid[idx] + sg * v;
                } else if (MODE == 2) {
                    ((unsigned short*)outv)[(size_t)m * 1024 + n] = f2bf(fmaxf(v + bs, 0.f));
                } else {
                    size_t idx = (size_t)m * 1024 + n;
                    ((float*)outv)[idx] = resid[idx] + sg * (v + bs);
                }
            }
        }
    }
}

// ---------------------------------------------------------------------------
// fp32 -> bf16 hi/lo split elementwise (x2 copy): hi = RNE(x), lo = RNE(x-hi)
// ---------------------------------------------------------------------------
__global__ __launch_bounds__(256)
void f2bf2_kernel(const float* __restrict__ in,
                  unsigned short* __restrict__ hi, unsigned short* __restrict__ lo) {
    size_t i = ((size_t)blockIdx.x * 256 + threadIdx.x) * 8;
    float4 a = *reinterpret_cast<const float4*>(&in[i]);
    float4 b = *reinterpret_cast<const float4*>(&in[i + 4]);
    float xs[8] = {a.x, a.y, a.z, a.w, b.x, b.y, b.z, b.w};
    ushort8 oh, ol;
#pragma unroll
    for (int e = 0; e < 8; ++e) {
        unsigned short h = f2bf(xs[e]);
        oh[e] = h;
        ol[e] = f2bf(xs[e] - bf2f(h));
    }
    *reinterpret_cast<ushort8*>(&hi[i]) = oh;
    *reinterpret_cast<ushort8*>(&lo[i]) = ol;
}

// ---------------------------------------------------------------------------
// Merged weight transpose (4 weights in one launch, z-indexed)
// ---------------------------------------------------------------------------
__global__ __launch_bounds__(256)
void wtrans4(const float* __restrict__ Wa, unsigned short* __restrict__ Ta,
             const float* __restrict__ Wb, unsigned short* __restrict__ Tb,
             const float* __restrict__ Wc, unsigned short* __restrict__ Tc,
             const float* __restrict__ Wd, unsigned short* __restrict__ Td) {
    const float* W; unsigned short* WT;
    switch (blockIdx.z) {
        case 0:  W = Wa; WT = Ta; break;
        case 1:  W = Wb; WT = Tb; break;
        case 2:  W = Wc; WT = Tc; break;
        default: W = Wd; WT = Td; break;
    }
    __shared__ float tile[32][33];
    int n0 = blockIdx.x * 32, k0 = blockIdx.y * 32;
    int lx = threadIdx.x & 31, ly = threadIdx.x >> 5;
#pragma unroll
    for (int i = 0; i < 4; ++i)
        tile[ly + i * 8][lx] = W[(size_t)(k0 + ly + i * 8) * 1024 + n0 + lx];
    __syncthreads();
#pragma unroll
    for (int i = 0; i < 4; ++i)
        WT[(size_t)(n0 + ly + i * 8) * 1024 + k0 + lx] = f2bf(tile[lx][ly + i * 8]);
}

// ---------------------------------------------------------------------------
// Weight transpose + RNE hi/lo split
// ---------------------------------------------------------------------------
__global__ __launch_bounds__(256)
void wtrans_split(const float* __restrict__ W,
                  unsigned short* __restrict__ WThi,
                  unsigned short* __restrict__ WTlo) {
    __shared__ float tile[32][33];
    int n0 = blockIdx.x * 32, k0 = blockIdx.y * 32;
    int lx = threadIdx.x & 31, ly = threadIdx.x >> 5;
#pragma unroll
    for (int i = 0; i < 4; ++i)
        tile[ly + i * 8][lx] = W[(size_t)(k0 + ly + i * 8) * 1024 + n0 + lx];
    __syncthreads();
#pragma unroll
    for (int i = 0; i < 4; ++i) {
        float x = tile[lx][ly + i * 8];
        size_t idx = (size_t)(n0 + ly + i * 8) * 1024 + k0 + lx;
        unsigned short h = f2bf(x);
        WThi[idx] = h;
        WTlo[idx] = f2bf(x - bf2f(h));
    }
}

// ---------------------------------------------------------------------------
// rot transpose + RNE hi/lo split: rot[h][r][d][m] f32 -> rotT[h][r*32+m][d]
// ---------------------------------------------------------------------------
__global__ __launch_bounds__(256)
void rott_kernel(const float* __restrict__ rot,
                 unsigned short* __restrict__ Th, unsigned short* __restrict__ Tl) {
    int hr = blockIdx.x;                 // h*4 + r, 0..63
    const float* src = rot + (size_t)hr * 64 * 32;
#pragma unroll
    for (int i = 0; i < 8; ++i) {
        int idx = threadIdx.x + i * 256;
        int d = idx >> 5, m = idx & 31;
        float x = src[idx];
        unsigned short hb = f2bf(x);
        size_t dst = ((size_t)(hr >> 2) * 128 + (hr & 3) * 32 + m) * 64 + d;
        Th[dst] = hb;
        Tl[dst] = f2bf(x - bf2f(hb));
    }
}

// ---------------------------------------------------------------------------
// MFMA buckets v2 (R21-validated): 512 threads / 8 waves.
// ---------------------------------------------------------------------------
__global__ __launch_bounds__(512)
void buckets_mfma(const float* __restrict__ qk,
                  const unsigned short* __restrict__ rotTh,
                  const unsigned short* __restrict__ rotTl,
                  int* __restrict__ buckets, unsigned short* __restrict__ qb,
                  float* __restrict__ qnorm) {
    __shared__ unsigned short Ah[128][72];
    __shared__ unsigned short Al[128][72];
    __shared__ unsigned short Bh[128][72];
    __shared__ unsigned short Bl[128][72];
    const int tid = threadIdx.x;
    const int bh = blockIdx.y;           // 0..31
    const int m0 = blockIdx.x * 128;     // token tile base
    const int h = bh & 15;
    const size_t bhS = (size_t)bh * S_;

    {
        int row = tid >> 2, qt = tid & 3;
        const unsigned short* sH = rotTh + ((size_t)h * 128 + row) * 64 + qt * 16;
        const unsigned short* sL = rotTl + ((size_t)h * 128 + row) * 64 + qt * 16;
#pragma unroll
        for (int u = 0; u < 2; ++u) {
            *reinterpret_cast<ushort8*>(&Bh[row][qt * 16 + u * 8]) =
                *reinterpret_cast<const ushort8*>(sH + u * 8);
            *reinterpret_cast<ushort8*>(&Bl[row][qt * 16 + u * 8]) =
                *reinterpret_cast<const ushort8*>(sL + u * 8);
        }
    }
    {
        int row = tid >> 2, qt = tid & 3;
        const float* src = qk + (bhS + m0 + row) * 64 + qt * 16;
        float ss = 0.f;
#pragma unroll
        for (int j = 0; j < 4; ++j) {
            float4 a4 = *reinterpret_cast<const float4*>(src + j * 4);
            ss += a4.x * a4.x + a4.y * a4.y + a4.z * a4.z + a4.w * a4.w;
            ushort4v h4, lo4;
            h4[0] = f2bf(a4.x); h4[1] = f2bf(a4.y); h4[2] = f2bf(a4.z); h4[3] = f2bf(a4.w);
            lo4[0] = f2bf(a4.x - bf2f(h4[0]));
            lo4[1] = f2bf(a4.y - bf2f(h4[1]));
            lo4[2] = f2bf(a4.z - bf2f(h4[2]));
            lo4[3] = f2bf(a4.w - bf2f(h4[3]));
            *reinterpret_cast<ushort4v*>(&Ah[row][qt * 16 + j * 4]) = h4;
            *reinterpret_cast<ushort4v*>(&Al[row][qt * 16 + j * 4]) = lo4;
            *reinterpret_cast<ushort4v*>(&qb[(bhS + m0 + row) * 64 + qt * 16 + j * 4]) = h4;
        }
        ss += __shfl_xor(ss, 1);
        ss += __shfl_xor(ss, 2);
        if (qt == 0) qnorm[bhS + m0 + row] = sqrtf(ss);
    }
    __syncthreads();

    const int lane = tid & 63, wv = tid >> 6;    // wv in [0,8)
    const int l15 = lane & 15, l4 = lane >> 4;

    f32x4 acc[8];
#pragma unroll
    for (int fn = 0; fn < 8; ++fn) acc[fn] = (f32x4)0.f;

#pragma unroll
    for (int ks = 0; ks < 2; ++ks) {
        bf16x8 ah = *reinterpret_cast<const bf16x8*>(&Ah[wv * 16 + l15][l4 * 8 + ks * 32]);
        bf16x8 al = *reinterpret_cast<const bf16x8*>(&Al[wv * 16 + l15][l4 * 8 + ks * 32]);
#pragma unroll
        for (int fn = 0; fn < 8; ++fn) {
            bf16x8 bh_ = *reinterpret_cast<const bf16x8*>(&Bh[fn * 16 + l15][l4 * 8 + ks * 32]);
            bf16x8 bl_ = *reinterpret_cast<const bf16x8*>(&Bl[fn * 16 + l15][l4 * 8 + ks * 32]);
            acc[fn] = __builtin_amdgcn_mfma_f32_16x16x32_bf16(ah, bh_, acc[fn], 0, 0, 0);
            acc[fn] = __builtin_amdgcn_mfma_f32_16x16x32_bf16(ah, bl_, acc[fn], 0, 0, 0);
            acc[fn] = __builtin_amdgcn_mfma_f32_16x16x32_bf16(al, bh_, acc[fn], 0, 0, 0);
        }
    }

#pragma unroll
    for (int r = 0; r < 4; ++r) {
#pragma unroll
        for (int q = 0; q < 4; ++q) {
            float v1 = acc[2 * r][q];
            float v2 = acc[2 * r + 1][q];
            float bv = v1; int bi = l15;
            if (v2  > bv) { bv = v2;  bi = 16 + l15; }
            if (-v1 > bv) { bv = -v1; bi = 32 + l15; }
            if (-v2 > bv) { bv = -v2; bi = 48 + l15; }
#pragma unroll
            for (int off = 1; off < 16; off <<= 1) {
                float ov = __shfl_xor(bv, off);
                int   oi = __shfl_xor(bi, off);
                if (ov > bv || (ov == bv && oi < bi)) { bv = ov; bi = oi; }
            }
            if (l15 == 0) {
                int row = wv * 16 + l4 * 4 + q;
                buckets[(size_t)(bh * 4 + r) * S_ + m0 + row] = bi;
            }
        }
    }
}

// ---------------------------------------------------------------------------
// Stable counting sort per group g: perm = argsort(bucket*S + pos)
// ---------------------------------------------------------------------------
__global__ __launch_bounds__(256)
void sort_kernel(const int* __restrict__ buckets, int* __restrict__ perm) {
    __shared__ int bk[4096];
    __shared__ int qcnt[4][64];
    __shared__ int qoff[4][64];
    __shared__ int ps[4096];
    int g = blockIdx.x, tid = threadIdx.x;
    const int* bp = buckets + (size_t)g * S_;
    for (int i = 0; i < 16; ++i) bk[tid + 256 * i] = bp[tid + 256 * i];
    qcnt[tid >> 6][tid & 63] = 0;
    __syncthreads();
    int q = tid >> 6, l = tid & 63;
    for (int i = 0; i < 16; ++i) {
        int pos = q * 1024 + l + 64 * i;
        atomicAdd(&qcnt[q][bk[pos]], 1);
    }
    __syncthreads();
    if (tid == 0) {
        int run = 0;
        for (int b = 0; b < 64; ++b)
            for (int qq = 0; qq < 4; ++qq) { qoff[qq][b] = run; run += qcnt[qq][b]; }
    }
    __syncthreads();
    {
        int base = qoff[q][l], cnt = 0;
        for (int j = q * 1024; j < q * 1024 + 1024; ++j) {
            if (bk[j] == l) { ps[base + cnt] = j; ++cnt; }
        }
    }
    __syncthreads();
    int* pp = perm + (size_t)g * S_;
    for (int i = 0; i < 16; ++i) pp[tid + 256 * i] = ps[tid + 256 * i];
}

// ---------------------------------------------------------------------------
// FUSED LSH attention -- ATOMIC-FREE (R16) + XCD swizzle (R14) + Vt
// XOR-swizzle (R20). NEW: Ks stride 72->70, P stride 136->134 u16 --
// read bank pattern becomes (3*l15 + 4*l4)%32 (~2-way, was 8-bank);
// P store covers all 32 banks. Bit-identical values.
// Layout: Ks[128][70] @0 (17920B, overlaps Vt head: disjoint lifetime);
// P[64][134] @0 (17152B); Vt[64][136] @17408.
// ---------------------------------------------------------------------------
__global__ __launch_bounds__(256)
void fused_attn(const unsigned short* __restrict__ qb,
                const unsigned short* __restrict__ vb,
                const int* __restrict__ perm,
                const float* __restrict__ qnorm,
                unsigned short* __restrict__ U4, float* __restrict__ D4) {
    __shared__ __align__(16) char smem[34816];
    unsigned short (*Ks)[70]  = (unsigned short (*)[70])smem;
    unsigned short (*P)[134]  = (unsigned short (*)[134])smem;
    unsigned short (*Vt)[136] = (unsigned short (*)[136])(smem + 17408);
    __shared__ int   toks[128];
    __shared__ float rk[128];
    __shared__ float qn_s[64];

    const int tid = threadIdx.x;
    const int bid = blockIdx.x;
    const int g = (bid & 7) * 16 + ((bid >> 3) & 15);
    const int c = bid >> 7;
    const int bh = g >> 2;
    const int pc = (c + 63) & 63;
    const size_t gS = (size_t)g * S_, bhS = (size_t)bh * S_;

    if (tid < 128) {
        toks[tid] = (tid < 64) ? perm[gS + c * 64 + tid]
                               : perm[gS + pc * 64 + (tid - 64)];
    }
    __syncthreads();
    if (tid < 128) {
        float qn = qnorm[bhS + toks[tid]];
        rk[tid] = SCALE_ / (qn + 1e-6f);
        if (tid < 64) qn_s[tid] = SCALE_ * qn;
    }
#pragma unroll
    for (int i = 0; i < 4; ++i) {
        int cc = tid + 256 * i;
        int row = cc >> 3, sub = cc & 7;
        ushort8 v = *reinterpret_cast<const ushort8*>(&qb[(bhS + toks[row]) * 64 + sub * 8]);
        *reinterpret_cast<ushort8*>(&Ks[row][sub * 8]) = v;
    }
    __syncthreads();

    const int lane = tid & 63, w = tid >> 6;
    const int l15 = lane & 15, l4 = lane >> 4;

    f32x4 accd[8];
#pragma unroll
    for (int fn = 0; fn < 8; ++fn) accd[fn] = (f32x4)0.f;
#pragma unroll
    for (int ks = 0; ks < 2; ++ks) {
        bf16x8 a = *reinterpret_cast<const bf16x8*>(&Ks[w * 16 + l15][l4 * 8 + ks * 32]);
#pragma unroll
        for (int fn = 0; fn < 8; ++fn) {
            bf16x8 b = *reinterpret_cast<const bf16x8*>(&Ks[fn * 16 + l15][l4 * 8 + ks * 32]);
            accd[fn] = __builtin_amdgcn_mfma_f32_16x16x32_bf16(a, b, accd[fn], 0, 0, 0);
        }
    }
    __syncthreads();   // Ks dead; LDS reused for P (and Vt region)

    float dsum[4] = {0.f, 0.f, 0.f, 0.f};
#pragma unroll
    for (int fn = 0; fn < 8; ++fn) {
        int j = fn * 16 + l15;
        float rj = rk[j];
#pragma unroll
        for (int q = 0; q < 4; ++q) {
            int i = w * 16 + l4 * 4 + q;
            float p = __expf(accd[fn][q] * rj - qn_s[i]);
            dsum[q] += p;
            P[i][j] = f2bf(p);
        }
    }
#pragma unroll
    for (int q = 0; q < 4; ++q) {
#pragma unroll
        for (int off = 1; off < 16; off <<= 1) dsum[q] += __shfl_xor(dsum[q], off);
    }
    if (l15 == 0) {
#pragma unroll
        for (int q = 0; q < 4; ++q)
            D4[gS + toks[w * 16 + l4 * 4 + q]] = dsum[q];    // plain store (exclusive owner)
    }
    // Vt transpose-store, XOR-swizzled: col = row ^ (sub<<3)
#pragma unroll
    for (int i = 0; i < 4; ++i) {
        int cc = tid + 256 * i;
        int row = cc >> 3, sub = cc & 7;
        ushort8 v = *reinterpret_cast<const ushort8*>(&vb[(bhS + toks[row]) * 64 + sub * 8]);
        int colx = row ^ (sub << 3);
#pragma unroll
        for (int e = 0; e < 8; ++e) Vt[sub * 8 + e][colx] = v[e];
    }
    __syncthreads();

    f32x4 acco[4];
#pragma unroll
    for (int fn = 0; fn < 4; ++fn) acco[fn] = (f32x4)0.f;
#pragma unroll
    for (int ks = 0; ks < 4; ++ks) {
        bf16x8 a = *reinterpret_cast<const bf16x8*>(&P[w * 16 + l15][l4 * 8 + ks * 32]);
#pragma unroll
        for (int fn = 0; fn < 4; ++fn) {
            int dh = fn * 16 + l15;
            int key = (dh >> 3) & 7;
            int colr = (l4 * 8 + ks * 32) ^ (key << 3);
            bf16x8 b = *reinterpret_cast<const bf16x8*>(&Vt[dh][colr]);
            acco[fn] = __builtin_amdgcn_mfma_f32_16x16x32_bf16(a, b, acco[fn], 0, 0, 0);
        }
    }
#pragma unroll
    for (int fn = 0; fn < 4; ++fn) {
        int dh = fn * 16 + l15;
#pragma unroll
        for (int q = 0; q < 4; ++q) {
            int i = w * 16 + l4 * 4 + q;
            U4[(gS + toks[i]) * 64 + dh] = f2bf(acco[fn][q]);  // plain store
        }
    }
}

// ---------------------------------------------------------------------------
// Mix v2 (R18-validated): 16-lane-group parallel; sums 4 per-round U/D.
// ---------------------------------------------------------------------------
__global__ __launch_bounds__(256)
void mix_staged(const unsigned short* __restrict__ qb, const float* __restrict__ qnorm,
                const unsigned short* __restrict__ vb,
                const unsigned short* __restrict__ U4, const float* __restrict__ D4,
                const float* __restrict__ w_gate, const float* __restrict__ b_gate,
                unsigned short* __restrict__ mixb, float* __restrict__ gpart) {
    __shared__ unsigned short kq[72][64];
    __shared__ unsigned short vvs[72][64];
    __shared__ float rns[72];
    __shared__ float gacc[4];
    const int tid = threadIdx.x;
    const int bh = blockIdx.y;           // 0..31
    const int s0 = blockIdx.x * 64;
    const int h = bh & 15, b = bh >> 4;
    const size_t bhS = (size_t)bh * S_;

    for (int c = tid; c < 576; c += 256) {          // 72 rows x 8 chunks
        int row = c >> 3, sub = c & 7;
        int idx = s0 - 4 + row;
        int ic = idx < 0 ? 0 : (idx > S_ - 1 ? S_ - 1 : idx);
        *reinterpret_cast<ushort8*>(&kq[row][sub * 8]) =
            *reinterpret_cast<const ushort8*>(&qb[(bhS + ic) * 64 + sub * 8]);
        *reinterpret_cast<ushort8*>(&vvs[row][sub * 8]) =
            *reinterpret_cast<const ushort8*>(&vb[(bhS + ic) * 64 + sub * 8]);
    }
    if (tid < 72) {
        int idx = s0 - 4 + tid;
        int ic = idx < 0 ? 0 : (idx > S_ - 1 ? S_ - 1 : idx);
        rns[tid] = 1.f / (qnorm[bhS + ic] + 1e-6f);
    }
    __syncthreads();

    const int wv = tid >> 6, lane = tid & 63;
    const int grp = lane >> 4, l15 = lane & 15;     // 4 groups of 16 per wave
    const int d0 = l15 * 4;                         // this lane's 4 dh values
    float4 wgl4 = *reinterpret_cast<const float4*>(&w_gate[h * 64 + d0]);
    const float bg = b_gate[h];
    float gsum = 0.f;

#pragma unroll
    for (int t4 = 0; t4 < 4; ++t4) {                // 16 tokens per iteration
        int t = t4 * 16 + wv * 4 + grp;             // unique token in [0,64)
        int s = s0 + t;
        float qd[4];
        {
            ushort4v q4 = *reinterpret_cast<const ushort4v*>(&kq[t + 4][d0]);
#pragma unroll
            for (int e = 0; e < 4; ++e) qd[e] = bf2f(q4[e]);
        }
        float pw[9];
        float4 vbv[9];
#pragma unroll
        for (int wt = 0; wt < 9; ++wt) {
            int idx = s - 4 + wt;
            bool valid = (idx >= 0) && (idx < S_);
            int ic = idx < 0 ? 0 : (idx > S_ - 1 ? S_ - 1 : idx);
            int r = ic - s0 + 4;
            ushort4v k4 = *reinterpret_cast<const ushort4v*>(&kq[r][d0]);
            float p = qd[0] * bf2f(k4[0]) + qd[1] * bf2f(k4[1])
                    + qd[2] * bf2f(k4[2]) + qd[3] * bf2f(k4[3]);
#pragma unroll
            for (int off = 1; off < 16; off <<= 1) p += __shfl_xor(p, off);
            pw[wt] = valid ? p * rns[r] * SCALE_ : -1e9f;
            ushort4v v4 = *reinterpret_cast<const ushort4v*>(&vvs[r][d0]);
            vbv[wt].x = bf2f(v4[0]); vbv[wt].y = bf2f(v4[1]);
            vbv[wt].z = bf2f(v4[2]); vbv[wt].w = bf2f(v4[3]);
        }
        float mx = pw[0];
#pragma unroll
        for (int wt = 1; wt < 9; ++wt) mx = fmaxf(mx, pw[wt]);
        float den = 0.f;
        float4 loc = make_float4(0.f, 0.f, 0.f, 0.f);
#pragma unroll
        for (int wt = 0; wt < 9; ++wt) {
            float e = __expf(pw[wt] - mx);
            den += e;
            loc.x += e * vbv[wt].x; loc.y += e * vbv[wt].y;
            loc.z += e * vbv[wt].z; loc.w += e * vbv[wt].w;
        }
        float rden = 1.f / den;
        loc.x *= rden; loc.y *= rden; loc.z *= rden; loc.w *= rden;

        float gv = qd[0] * wgl4.x + qd[1] * wgl4.y + qd[2] * wgl4.z + qd[3] * wgl4.w;
#pragma unroll
        for (int off = 1; off < 16; off <<= 1) gv += __shfl_xor(gv, off);
        float gg = sigf(gv + bg);

        float un[4] = {0.f, 0.f, 0.f, 0.f};
        float dd = 0.f;
#pragma unroll
        for (int r = 0; r < 4; ++r) {
            size_t grow = ((size_t)(bh * 4 + r) * S_ + s);
            ushort4v u4 = *reinterpret_cast<const ushort4v*>(&U4[grow * 64 + d0]);
#pragma unroll
            for (int e = 0; e < 4; ++e) un[e] += bf2f(u4[e]);
            dd += D4[grow];
        }
        float rdd = 1.f / dd;
        float og = 1.f - gg;
        ushort4v o;
        o[0] = f2bf(gg * loc.x + og * un[0] * rdd);
        o[1] = f2bf(gg * loc.y + og * un[1] * rdd);
        o[2] = f2bf(gg * loc.z + og * un[2] * rdd);
        o[3] = f2bf(gg * loc.w + og * un[3] * rdd);
        *reinterpret_cast<ushort4v*>(&mixb[((size_t)b * S_ + s) * 1024 + h * 64 + d0]) = o;
        if (l15 == 0) gsum += gg * (1.f - gg);
    }
#pragma unroll
    for (int off = 32; off; off >>= 1) gsum += __shfl_xor(gsum, off);
    if (lane == 0) gacc[wv] = gsum;
    __syncthreads();
    if (tid == 0)
        gpart[blockIdx.y * 64 + blockIdx.x] = gacc[0] + gacc[1] + gacc[2] + gacc[3];
}

__global__ __launch_bounds__(256)
void reg_reduce(const float* __restrict__ gpart, float* __restrict__ outreg) {
    __shared__ float part[4];
    float sm = 0.f;
    for (int i = threadIdx.x; i < 2048; i += 256) sm += gpart[i];
#pragma unroll
    for (int off = 32; off; off >>= 1) sm += __shfl_xor(sm, off);
    if ((threadIdx.x & 63) == 0) part[threadIdx.x >> 6] = sm;
    __syncthreads();
    if (threadIdx.x == 0) outreg[0] = (part[0] + part[1] + part[2] + part[3]) * (1.f / 131072.f);
}

// ---------------------------------------------------------------------------
// LayerNorm over D=1024, block per row; bf16 out
// ---------------------------------------------------------------------------
__global__ __launch_bounds__(256)
void ln_kernel(const float* __restrict__ x, const float* __restrict__ gg,
               const float* __restrict__ bb, unsigned short* __restrict__ outp) {
    __shared__ float ps[4][2];
    int row = blockIdx.x, tid = threadIdx.x;
    int wv = tid >> 6, lane = tid & 63;
    const float* xr = x + (size_t)row * 1024;
    float4 xv = *reinterpret_cast<const float4*>(&xr[tid * 4]);
    float s = xv.x + xv.y + xv.z + xv.w;
    float s2 = xv.x * xv.x + xv.y * xv.y + xv.z * xv.z + xv.w * xv.w;
#pragma unroll
    for (int off = 32; off; off >>= 1) { s += __shfl_xor(s, off); s2 += __shfl_xor(s2, off); }
    if (lane == 0) { ps[wv][0] = s; ps[wv][1] = s2; }
    __syncthreads();
    s  = ps[0][0] + ps[1][0] + ps[2][0] + ps[3][0];
    s2 = ps[0][1] + ps[1][1] + ps[2][1] + ps[3][1];
    float mean = s * (1.f / 1024.f);
    float var = s2 * (1.f / 1024.f) - mean * mean;
    float rs = rsqrtf(var + 1e-5f);
    float4 gv = *reinterpret_cast<const float4*>(&gg[tid * 4]);
    float4 bv = *reinterpret_cast<const float4*>(&bb[tid * 4]);
    ushort4v o;
    o[0] = f2bf((xv.x - mean) * rs * gv.x + bv.x);
    o[1] = f2bf((xv.y - mean) * rs * gv.y + bv.y);
    o[2] = f2bf((xv.z - mean) * rs * gv.z + bv.z);
    o[3] = f2bf((xv.w - mean) * rs * gv.w + bv.w);
    *reinterpret_cast<ushort4v*>(&outp[(size_t)row * 1024 + tid * 4]) = o;
}

// ---------------------------------------------------------------------------
// Buffer plan (R22):
//  d_out[0:BSD]   = qk (phase 1) -> U4 lower half -> y1
//  d_out[BSD:2BSD]= x2lo bf16 (phase 1, dead after qk_split) -> U4 upper -> y2
//  ws A 0:        x2b -> qb -> tb      ws B 16777216: vbuf -> hb
//  ws C 33554432: WqkTh/WqkTl -> buckets -> mixb
//  ws D 50331648: WvT (-> D4 after gemm<0>) / WoT / W1T / W2T
//  ws E 58720256: perm    F 60817408: qnorm (0.5MB)
//  61341696: rotTh (0.25MB)   61603840: rotTl (0.25MB)   61865984: gpart
// ---------------------------------------------------------------------------
extern "C" void kernel_launch(void* const* d_in, const int* in_sizes, int n_in,
                              void* d_out, int out_size, void* d_ws, size_t ws_size,
                              hipStream_t stream) {
    (void)in_sizes; (void)n_in; (void)out_size; (void)ws_size;
    const float* x1    = (const float*)d_in[0];
    const float* x2    = (const float*)d_in[1];
    const float* Wqk   = (const float*)d_in[2];
    const float* Wv    = (const float*)d_in[3];
    const float* Wo    = (const float*)d_in[4];
    const float* rot   = (const float*)d_in[5];
    const float* w_gate= (const float*)d_in[6];
    const float* b_gate= (const float*)d_in[7];
    const float* ln_g  = (const float*)d_in[8];
    const float* ln_b  = (const float*)d_in[9];
    const float* W1    = (const float*)d_in[10];
    const float* b1    = (const float*)d_in[11];
    const float* W2    = (const float*)d_in[12];
    const float* b2    = (const float*)d_in[13];
    const float* alpha = (const float*)d_in[14];
    const float* beta  = (const float*)d_in[15];

    float* out = (float*)d_out;
    float* qk  = out;                              // dead after buckets_mfma
    unsigned short* x2lo = (unsigned short*)(out + (size_t)BSD_);  // dead after qk_split
    unsigned short* U4 = (unsigned short*)out;     // 67 MB during attention
    float* y1  = out;
    float* y2  = out + (size_t)BSD_;

    char* ws = (char*)d_ws;
    unsigned short* x2b   = (unsigned short*)(ws + 0);
    unsigned short* qb    = (unsigned short*)(ws + 0);
    unsigned short* tb    = (unsigned short*)(ws + 0);
    unsigned short* vbuf  = (unsigned short*)(ws + 16777216);
    unsigned short* hb    = (unsigned short*)(ws + 16777216);
    unsigned short* WqkTh = (unsigned short*)(ws + 33554432);   // dead before buckets
    unsigned short* WqkTl = (unsigned short*)(ws + 35651584);
    int*   buckets        = (int*)  (ws + 33554432);
    unsigned short* mixb  = (unsigned short*)(ws + 33554432);
    unsigned short* WvT   = (unsigned short*)(ws + 50331648);   // dead after gemm<0>
    float* D4             = (float*) (ws + 50331648);           // 2 MB, reuses WvT slot
    unsigned short* WoT   = (unsigned short*)(ws + 52428800);
    unsigned short* W1T   = (unsigned short*)(ws + 54525952);
    unsigned short* W2T   = (unsigned short*)(ws + 56623104);
    int*   perm           = (int*)  (ws + 58720256);
    float* qnorm          = (float*)(ws + 60817408);
    unsigned short* rotTh = (unsigned short*)(ws + 61341696);   // 0.25 MB
    unsigned short* rotTl = (unsigned short*)(ws + 61603840);   // 0.25 MB
    float* gpart          = (float*)(ws + 61865984);

    dim3 gb(256);
    // x2 -> (hi, lo) bf16; hi == old x2b bit-exactly
    f2bf2_kernel<<<4096, 256, 0, stream>>>(x2, x2b, x2lo);
    wtrans_split<<<dim3(32, 32), 256, 0, stream>>>(Wqk, WqkTh, WqkTl);
    wtrans4<<<dim3(32, 32, 4), 256, 0, stream>>>(Wv, WvT, Wo, WoT, W1, W1T, W2, W2T);
    rott_kernel<<<64, 256, 0, stream>>>(rot, rotTh, rotTl);

    // qk split-GEMM + v GEMM: XCD-chunked 1D grids (512 blocks)
    gemm_qk_split<<<512, gb, 0, stream>>>(x2b, x2lo, WqkTh, WqkTl, qk);
    gemm_bf16<0><<<512, gb, 0, stream>>>(x2b, WvT, vbuf, nullptr, nullptr, nullptr);

    // MFMA buckets (all 4 rounds) + qnorm + qb; 8-wave blocks (R21)
    buckets_mfma<<<dim3(32, 32), 512, 0, stream>>>(qk, rotTh, rotTl, buckets, qb, qnorm);
    sort_kernel<<<128, 256, 0, stream>>>(buckets, perm);

    // atomic-free attention: per-round exclusive plain stores (overwrites qk+x2lo)
    fused_attn<<<8192, 256, 0, stream>>>(qb, vbuf, perm, qnorm, U4, D4);

    mix_staged<<<dim3(64, 32), 256, 0, stream>>>(qb, qnorm, vbuf, U4, D4,
                                                 w_gate, b_gate, mixb, gpart);
    reg_reduce<<<1, 256, 0, stream>>>(gpart, out + 2 * (size_t)BSD_);

    gemm_bf16<1><<<512, gb, 0, stream>>>(mixb, WoT, y1, nullptr, x1, alpha);
    ln_kernel<<<8192, 256, 0, stream>>>(y1, ln_g, ln_b, hb);
    gemm_bf16<2><<<512, gb, 0, stream>>>(hb, W1T, tb, b1, nullptr, nullptr);
    gemm_bf16<3><<<512, gb, 0, stream>>>(tb, W2T, y2, b2, x2, beta);
}

// Round 24
// 379.749 us; speedup vs baseline: 1.1783x; 1.1783x over previous
//
#include <hip/hip_runtime.h>
#include <math.h>

#define B_    2
#define S_    4096
#define D_    1024
#define H_    16
#define DH_   64
#define NH_   4
#define BSD_  8388608     // B*S*D
#define SCALE_ 0.125f     // DH^-0.5

typedef __attribute__((ext_vector_type(8))) short   bf16x8;   // 8 bf16 (4 VGPR)
typedef __attribute__((ext_vector_type(4))) float   f32x4;
typedef __attribute__((ext_vector_type(8))) unsigned short ushort8;
typedef __attribute__((ext_vector_type(4))) unsigned short ushort4v;

__device__ __forceinline__ float sigf(float x) { return 1.f / (1.f + expf(-x)); }

__device__ __forceinline__ unsigned short f2bf(float f) {   // RNE float->bf16 bits
    union { float f; unsigned u; } v; v.f = f;
    unsigned r = v.u + 0x7FFF + ((v.u >> 16) & 1);
    return (unsigned short)(r >> 16);
}
__device__ __forceinline__ float bf2f(unsigned short u) {
    union { unsigned u; float f; } v; v.u = ((unsigned)u) << 16; return v.f;
}

__device__ __forceinline__ void gload_lds16(const void* g, void* l) {
    __builtin_amdgcn_global_load_lds(
        (const __attribute__((address_space(1))) void*)(g),
        (__attribute__((address_space(3))) void*)(l),
        16, 0, 0);
}

// XCD-chunked 1D-grid remap for M=8192,N=1024 GEMMs (512 blocks):
// each XCD (bid%8) owns 64 consecutive logical tiles = 8 A-row-panels x all x.
// (R23-validated: ~12us total GEMM gain; bit-identical remap.)
__device__ __forceinline__ void gemm_tile_remap(int bid, int& m0, int& n0) {
    int logical = (bid & 7) * 64 + (bid >> 3);
    m0 = (logical >> 3) * 128;
    n0 = (logical & 7) * 128;
}

// ---------------------------------------------------------------------------
// Split-precision qk GEMM (RNE hi/lo, 3 MFMA) -- A pre-split (R22-validated),
// pure global_load_lds staging; XCD-chunked grid.
// ---------------------------------------------------------------------------
__global__ __launch_bounds__(256)
void gemm_qk_split(const unsigned short* __restrict__ Ahg,
                   const unsigned short* __restrict__ Alg,
                   const unsigned short* __restrict__ BTh,
                   const unsigned short* __restrict__ BTl,
                   float* __restrict__ out) {
    __shared__ __align__(16) unsigned short Ah[128 * 32];
    __shared__ __align__(16) unsigned short Al[128 * 32];
    __shared__ __align__(16) unsigned short Bh[128 * 32];
    __shared__ __align__(16) unsigned short Bl[128 * 32];
    const int tid = threadIdx.x;
    const int lane = tid & 63, w = tid >> 6;
    const int wr = w >> 1, wc = w & 1;
    int m0, n0;
    gemm_tile_remap(blockIdx.x, m0, n0);
    const int l15 = lane & 15, lq = lane >> 4;

    f32x4 acc[4][4];
#pragma unroll
    for (int i = 0; i < 4; ++i)
#pragma unroll
        for (int j = 0; j < 4; ++j) acc[i][j] = (f32x4)0.f;

    for (int kt = 0; kt < 1024; kt += 32) {
#pragma unroll
        for (int i = 0; i < 2; ++i) {
            int d = i * 256 + tid;               // 16B chunk 0..511
            int r = d >> 2, sl = d & 3;
            size_t ga = (size_t)(m0 + r) * 1024 + kt + sl * 8;
            size_t gb = (size_t)(n0 + r) * 1024 + kt + sl * 8;
            gload_lds16(&Ahg[ga], &Ah[(size_t)d * 8]);
            gload_lds16(&Alg[ga], &Al[(size_t)d * 8]);
            gload_lds16(&BTh[gb], &Bh[(size_t)d * 8]);
            gload_lds16(&BTl[gb], &Bl[(size_t)d * 8]);
        }
        __syncthreads();
        bf16x8 afh[4], afl[4], bfh[4], bfl[4];
#pragma unroll
        for (int f = 0; f < 4; ++f) {
            int ar = (wr * 64 + f * 16 + l15) * 32 + lq * 8;
            int br = (wc * 64 + f * 16 + l15) * 32 + lq * 8;
            afh[f] = *reinterpret_cast<const bf16x8*>(&Ah[ar]);
            afl[f] = *reinterpret_cast<const bf16x8*>(&Al[ar]);
            bfh[f] = *reinterpret_cast<const bf16x8*>(&Bh[br]);
            bfl[f] = *reinterpret_cast<const bf16x8*>(&Bl[br]);
        }
#pragma unroll
        for (int fm = 0; fm < 4; ++fm)
#pragma unroll
            for (int fn = 0; fn < 4; ++fn) {
                acc[fm][fn] = __builtin_amdgcn_mfma_f32_16x16x32_bf16(afh[fm], bfh[fn], acc[fm][fn], 0, 0, 0);
                acc[fm][fn] = __builtin_amdgcn_mfma_f32_16x16x32_bf16(afh[fm], bfl[fn], acc[fm][fn], 0, 0, 0);
                acc[fm][fn] = __builtin_amdgcn_mfma_f32_16x16x32_bf16(afl[fm], bfh[fn], acc[fm][fn], 0, 0, 0);
            }
        __syncthreads();
    }

#pragma unroll
    for (int fn = 0; fn < 4; ++fn) {
        int n = n0 + wc * 64 + fn * 16 + l15;
        int h = n >> 6, dh = n & 63;
#pragma unroll
        for (int fm = 0; fm < 4; ++fm) {
#pragma unroll
            for (int q = 0; q < 4; ++q) {
                int m = m0 + wr * 64 + fm * 16 + lq * 4 + q;
                int bb = m >> 12, s = m & 4095;
                out[((((size_t)bb * H_ + h) * S_ + s) << 6) + dh] = acc[fm][fn][q];
            }
        }
    }
}

// ---------------------------------------------------------------------------
// bf16 MFMA GEMM, 128x128 tile, BK=64, XOR-swizzled LDS; XCD-chunked grid.
// MODE 0: out bf16 head-layout                       (v = x2 @ Wv)
// MODE 1: out fp32 = resid + sigf(gate[n]) * acc     (y1)
// MODE 2: out bf16 = relu(acc + bias[n])             (t)
// MODE 3: out fp32 = resid + sigf(gate[n])*(acc+bias)(y2)
// ---------------------------------------------------------------------------
template<int MODE>
__global__ __launch_bounds__(256)
void gemm_bf16(const unsigned short* __restrict__ A,
               const unsigned short* __restrict__ BT,
               void* __restrict__ outv,
               const float* __restrict__ bias,
               const float* __restrict__ resid,
               const float* __restrict__ gatev) {
    __shared__ __align__(16) unsigned short Als[128 * 64];
    __shared__ __align__(16) unsigned short Bls[128 * 64];
    const int tid = threadIdx.x;
    const int lane = tid & 63, w = tid >> 6;
    const int wr = w >> 1, wc = w & 1;
    int m0, n0;
    gemm_tile_remap(blockIdx.x, m0, n0);
    const int l15 = lane & 15, l4 = lane >> 4;

    f32x4 acc[4][4];
#pragma unroll
    for (int i = 0; i < 4; ++i)
#pragma unroll
        for (int j = 0; j < 4; ++j) acc[i][j] = (f32x4)0.f;

    for (int kt = 0; kt < 1024; kt += 64) {
#pragma unroll
        for (int i = 0; i < 4; ++i) {
            int d = i * 256 + tid;               // 16B chunk 0..1023
            int r = d >> 3, sl = d & 7;
            int ssl = sl ^ (r & 7);              // pre-swizzled source slot
            gload_lds16(&A [(size_t)(m0 + r) * 1024 + kt + ssl * 8], &Als[(size_t)d * 8]);
            gload_lds16(&BT[(size_t)(n0 + r) * 1024 + kt + ssl * 8], &Bls[(size_t)d * 8]);
        }
        __syncthreads();
#pragma unroll
        for (int ks = 0; ks < 2; ++ks) {
            bf16x8 af[4], bfr[4];
#pragma unroll
            for (int f = 0; f < 4; ++f) {
                int ra = wr * 64 + f * 16 + l15;
                int rb = wc * 64 + f * 16 + l15;
                int sa = (ks * 4 + l4) ^ (ra & 7);
                int sb = (ks * 4 + l4) ^ (rb & 7);
                af[f]  = *reinterpret_cast<const bf16x8*>(&Als[(size_t)ra * 64 + sa * 8]);
                bfr[f] = *reinterpret_cast<const bf16x8*>(&Bls[(size_t)rb * 64 + sb * 8]);
            }
#pragma unroll
            for (int fm = 0; fm < 4; ++fm)
#pragma unroll
                for (int fn = 0; fn < 4; ++fn)
                    acc[fm][fn] = __builtin_amdgcn_mfma_f32_16x16x32_bf16(af[fm], bfr[fn], acc[fm][fn], 0, 0, 0);
        }
        __syncthreads();
    }

#pragma unroll
    for (int fn = 0; fn < 4; ++fn) {
        int n = n0 + wc * 64 + fn * 16 + l15;
        float sg = 0.f, bs = 0.f;
        if (MODE == 1) sg = sigf(gatev[n]);
        if (MODE == 2) bs = bias[n];
        if (MODE == 3) { sg = sigf(gatev[n]); bs = bias[n]; }
#pragma unroll
        for (int fm = 0; fm < 4; ++fm) {
#pragma unroll
            for (int q = 0; q < 4; ++q) {
                int m = m0 + wr * 64 + fm * 16 + l4 * 4 + q;
                float v = acc[fm][fn][q];
                if (MODE == 0) {
                    int bb = m >> 12, s = m & 4095;
                    int h = n >> 6, dh = n & 63;
                    ((unsigned short*)outv)[((((size_t)bb * H_ + h) * S_ + s) << 6) + dh] = f2bf(v);
                } else if (MODE == 1) {
                    size_t idx = (size_t)m * 1024 + n;
                    ((float*)outv)[idx] = resid[idx] + sg * v;
                } else if (MODE == 2) {
                    ((unsigned short*)outv)[(size_t)m * 1024 + n] = f2bf(fmaxf(v + bs, 0.f));
                } else {
                    size_t idx = (size_t)m * 1024 + n;
                    ((float*)outv)[idx] = resid[idx] + sg * (v + bs);
                }
            }
        }
    }
}

// ---------------------------------------------------------------------------
// fp32 -> bf16 hi/lo split elementwise (x2 copy): hi = RNE(x), lo = RNE(x-hi)
// ---------------------------------------------------------------------------
__global__ __launch_bounds__(256)
void f2bf2_kernel(const float* __restrict__ in,
                  unsigned short* __restrict__ hi, unsigned short* __restrict__ lo) {
    size_t i = ((size_t)blockIdx.x * 256 + threadIdx.x) * 8;
    float4 a = *reinterpret_cast<const float4*>(&in[i]);
    float4 b = *reinterpret_cast<const float4*>(&in[i + 4]);
    float xs[8] = {a.x, a.y, a.z, a.w, b.x, b.y, b.z, b.w};
    ushort8 oh, ol;
#pragma unroll
    for (int e = 0; e < 8; ++e) {
        unsigned short h = f2bf(xs[e]);
        oh[e] = h;
        ol[e] = f2bf(xs[e] - bf2f(h));
    }
    *reinterpret_cast<ushort8*>(&hi[i]) = oh;
    *reinterpret_cast<ushort8*>(&lo[i]) = ol;
}

// ---------------------------------------------------------------------------
// Merged weight transpose (4 weights in one launch, z-indexed)
// ---------------------------------------------------------------------------
__global__ __launch_bounds__(256)
void wtrans4(const float* __restrict__ Wa, unsigned short* __restrict__ Ta,
             const float* __restrict__ Wb, unsigned short* __restrict__ Tb,
             const float* __restrict__ Wc, unsigned short* __restrict__ Tc,
             const float* __restrict__ Wd, unsigned short* __restrict__ Td) {
    const float* W; unsigned short* WT;
    switch (blockIdx.z) {
        case 0:  W = Wa; WT = Ta; break;
        case 1:  W = Wb; WT = Tb; break;
        case 2:  W = Wc; WT = Tc; break;
        default: W = Wd; WT = Td; break;
    }
    __shared__ float tile[32][33];
    int n0 = blockIdx.x * 32, k0 = blockIdx.y * 32;
    int lx = threadIdx.x & 31, ly = threadIdx.x >> 5;
#pragma unroll
    for (int i = 0; i < 4; ++i)
        tile[ly + i * 8][lx] = W[(size_t)(k0 + ly + i * 8) * 1024 + n0 + lx];
    __syncthreads();
#pragma unroll
    for (int i = 0; i < 4; ++i)
        WT[(size_t)(n0 + ly + i * 8) * 1024 + k0 + lx] = f2bf(tile[lx][ly + i * 8]);
}

// ---------------------------------------------------------------------------
// Weight transpose + RNE hi/lo split
// ---------------------------------------------------------------------------
__global__ __launch_bounds__(256)
void wtrans_split(const float* __restrict__ W,
                  unsigned short* __restrict__ WThi,
                  unsigned short* __restrict__ WTlo) {
    __shared__ float tile[32][33];
    int n0 = blockIdx.x * 32, k0 = blockIdx.y * 32;
    int lx = threadIdx.x & 31, ly = threadIdx.x >> 5;
#pragma unroll
    for (int i = 0; i < 4; ++i)
        tile[ly + i * 8][lx] = W[(size_t)(k0 + ly + i * 8) * 1024 + n0 + lx];
    __syncthreads();
#pragma unroll
    for (int i = 0; i < 4; ++i) {
        float x = tile[lx][ly + i * 8];
        size_t idx = (size_t)(n0 + ly + i * 8) * 1024 + k0 + lx;
        unsigned short h = f2bf(x);
        WThi[idx] = h;
        WTlo[idx] = f2bf(x - bf2f(h));
    }
}

// ---------------------------------------------------------------------------
// rot transpose + RNE hi/lo split: rot[h][r][d][m] f32 -> rotT[h][r*32+m][d]
// ---------------------------------------------------------------------------
__global__ __launch_bounds__(256)
void rott_kernel(const float* __restrict__ rot,
                 unsigned short* __restrict__ Th, unsigned short* __restrict__ Tl) {
    int hr = blockIdx.x;                 // h*4 + r, 0..63
    const float* src = rot + (size_t)hr * 64 * 32;
#pragma unroll
    for (int i = 0; i < 8; ++i) {
        int idx = threadIdx.x + i * 256;
        int d = idx >> 5, m = idx & 31;
        float x = src[idx];
        unsigned short hb = f2bf(x);
        size_t dst = ((size_t)(hr >> 2) * 128 + (hr & 3) * 32 + m) * 64 + d;
        Th[dst] = hb;
        Tl[dst] = f2bf(x - bf2f(hb));
    }
}

// ---------------------------------------------------------------------------
// MFMA buckets v2 (R21-validated): 512 threads / 8 waves.
// ---------------------------------------------------------------------------
__global__ __launch_bounds__(512)
void buckets_mfma(const float* __restrict__ qk,
                  const unsigned short* __restrict__ rotTh,
                  const unsigned short* __restrict__ rotTl,
                  int* __restrict__ buckets, unsigned short* __restrict__ qb,
                  float* __restrict__ qnorm) {
    __shared__ unsigned short Ah[128][72];
    __shared__ unsigned short Al[128][72];
    __shared__ unsigned short Bh[128][72];
    __shared__ unsigned short Bl[128][72];
    const int tid = threadIdx.x;
    const int bh = blockIdx.y;           // 0..31
    const int m0 = blockIdx.x * 128;     // token tile base
    const int h = bh & 15;
    const size_t bhS = (size_t)bh * S_;

    {
        int row = tid >> 2, qt = tid & 3;
        const unsigned short* sH = rotTh + ((size_t)h * 128 + row) * 64 + qt * 16;
        const unsigned short* sL = rotTl + ((size_t)h * 128 + row) * 64 + qt * 16;
#pragma unroll
        for (int u = 0; u < 2; ++u) {
            *reinterpret_cast<ushort8*>(&Bh[row][qt * 16 + u * 8]) =
                *reinterpret_cast<const ushort8*>(sH + u * 8);
            *reinterpret_cast<ushort8*>(&Bl[row][qt * 16 + u * 8]) =
                *reinterpret_cast<const ushort8*>(sL + u * 8);
        }
    }
    {
        int row = tid >> 2, qt = tid & 3;
        const float* src = qk + (bhS + m0 + row) * 64 + qt * 16;
        float ss = 0.f;
#pragma unroll
        for (int j = 0; j < 4; ++j) {
            float4 a4 = *reinterpret_cast<const float4*>(src + j * 4);
            ss += a4.x * a4.x + a4.y * a4.y + a4.z * a4.z + a4.w * a4.w;
            ushort4v h4, lo4;
            h4[0] = f2bf(a4.x); h4[1] = f2bf(a4.y); h4[2] = f2bf(a4.z); h4[3] = f2bf(a4.w);
            lo4[0] = f2bf(a4.x - bf2f(h4[0]));
            lo4[1] = f2bf(a4.y - bf2f(h4[1]));
            lo4[2] = f2bf(a4.z - bf2f(h4[2]));
            lo4[3] = f2bf(a4.w - bf2f(h4[3]));
            *reinterpret_cast<ushort4v*>(&Ah[row][qt * 16 + j * 4]) = h4;
            *reinterpret_cast<ushort4v*>(&Al[row][qt * 16 + j * 4]) = lo4;
            *reinterpret_cast<ushort4v*>(&qb[(bhS + m0 + row) * 64 + qt * 16 + j * 4]) = h4;
        }
        ss += __shfl_xor(ss, 1);
        ss += __shfl_xor(ss, 2);
        if (qt == 0) qnorm[bhS + m0 + row] = sqrtf(ss);
    }
    __syncthreads();

    const int lane = tid & 63, wv = tid >> 6;    // wv in [0,8)
    const int l15 = lane & 15, l4 = lane >> 4;

    f32x4 acc[8];
#pragma unroll
    for (int fn = 0; fn < 8; ++fn) acc[fn] = (f32x4)0.f;

#pragma unroll
    for (int ks = 0; ks < 2; ++ks) {
        bf16x8 ah = *reinterpret_cast<const bf16x8*>(&Ah[wv * 16 + l15][l4 * 8 + ks * 32]);
        bf16x8 al = *reinterpret_cast<const bf16x8*>(&Al[wv * 16 + l15][l4 * 8 + ks * 32]);
#pragma unroll
        for (int fn = 0; fn < 8; ++fn) {
            bf16x8 bh_ = *reinterpret_cast<const bf16x8*>(&Bh[fn * 16 + l15][l4 * 8 + ks * 32]);
            bf16x8 bl_ = *reinterpret_cast<const bf16x8*>(&Bl[fn * 16 + l15][l4 * 8 + ks * 32]);
            acc[fn] = __builtin_amdgcn_mfma_f32_16x16x32_bf16(ah, bh_, acc[fn], 0, 0, 0);
            acc[fn] = __builtin_amdgcn_mfma_f32_16x16x32_bf16(ah, bl_, acc[fn], 0, 0, 0);
            acc[fn] = __builtin_amdgcn_mfma_f32_16x16x32_bf16(al, bh_, acc[fn], 0, 0, 0);
        }
    }

#pragma unroll
    for (int r = 0; r < 4; ++r) {
#pragma unroll
        for (int q = 0; q < 4; ++q) {
            float v1 = acc[2 * r][q];
            float v2 = acc[2 * r + 1][q];
            float bv = v1; int bi = l15;
            if (v2  > bv) { bv = v2;  bi = 16 + l15; }
            if (-v1 > bv) { bv = -v1; bi = 32 + l15; }
            if (-v2 > bv) { bv = -v2; bi = 48 + l15; }
#pragma unroll
            for (int off = 1; off < 16; off <<= 1) {
                float ov = __shfl_xor(bv, off);
                int   oi = __shfl_xor(bi, off);
                if (ov > bv || (ov == bv && oi < bi)) { bv = ov; bi = oi; }
            }
            if (l15 == 0) {
                int row = wv * 16 + l4 * 4 + q;
                buckets[(size_t)(bh * 4 + r) * S_ + m0 + row] = bi;
            }
        }
    }
}

// ---------------------------------------------------------------------------
// Stable counting sort per group g: perm = argsort(bucket*S + pos)
// ---------------------------------------------------------------------------
__global__ __launch_bounds__(256)
void sort_kernel(const int* __restrict__ buckets, int* __restrict__ perm) {
    __shared__ int bk[4096];
    __shared__ int qcnt[4][64];
    __shared__ int qoff[4][64];
    __shared__ int ps[4096];
    int g = blockIdx.x, tid = threadIdx.x;
    const int* bp = buckets + (size_t)g * S_;
    for (int i = 0; i < 16; ++i) bk[tid + 256 * i] = bp[tid + 256 * i];
    qcnt[tid >> 6][tid & 63] = 0;
    __syncthreads();
    int q = tid >> 6, l = tid & 63;
    for (int i = 0; i < 16; ++i) {
        int pos = q * 1024 + l + 64 * i;
        atomicAdd(&qcnt[q][bk[pos]], 1);
    }
    __syncthreads();
    if (tid == 0) {
        int run = 0;
        for (int b = 0; b < 64; ++b)
            for (int qq = 0; qq < 4; ++qq) { qoff[qq][b] = run; run += qcnt[qq][b]; }
    }
    __syncthreads();
    {
        int base = qoff[q][l], cnt = 0;
        for (int j = q * 1024; j < q * 1024 + 1024; ++j) {
            if (bk[j] == l) { ps[base + cnt] = j; ++cnt; }
        }
    }
    __syncthreads();
    int* pp = perm + (size_t)g * S_;
    for (int i = 0; i < 16; ++i) pp[tid + 256 * i] = ps[tid + 256 * i];
}

// ---------------------------------------------------------------------------
// FUSED LSH attention -- ATOMIC-FREE (R16) + XCD swizzle (R14) + Vt
// XOR-swizzle. R22-exact LDS layout restored (72/136 u16 rows = 16B-aligned;
// R23's 70/134 strides broke ds_read_b128 alignment -> 2x time).
// ---------------------------------------------------------------------------
__global__ __launch_bounds__(256)
void fused_attn(const unsigned short* __restrict__ qb,
                const unsigned short* __restrict__ vb,
                const int* __restrict__ perm,
                const float* __restrict__ qnorm,
                unsigned short* __restrict__ U4, float* __restrict__ D4) {
    __shared__ __align__(16) char smem[34816];
    unsigned short (*Ks)[72]  = (unsigned short (*)[72])smem;
    unsigned short (*P)[136]  = (unsigned short (*)[136])smem;
    unsigned short (*Vt)[136] = (unsigned short (*)[136])(smem + 17408);
    __shared__ int   toks[128];
    __shared__ float rk[128];
    __shared__ float qn_s[64];

    const int tid = threadIdx.x;
    const int bid = blockIdx.x;
    const int g = (bid & 7) * 16 + ((bid >> 3) & 15);
    const int c = bid >> 7;
    const int bh = g >> 2;
    const int pc = (c + 63) & 63;
    const size_t gS = (size_t)g * S_, bhS = (size_t)bh * S_;

    if (tid < 128) {
        toks[tid] = (tid < 64) ? perm[gS + c * 64 + tid]
                               : perm[gS + pc * 64 + (tid - 64)];
    }
    __syncthreads();
    if (tid < 128) {
        float qn = qnorm[bhS + toks[tid]];
        rk[tid] = SCALE_ / (qn + 1e-6f);
        if (tid < 64) qn_s[tid] = SCALE_ * qn;
    }
#pragma unroll
    for (int i = 0; i < 4; ++i) {
        int cc = tid + 256 * i;
        int row = cc >> 3, sub = cc & 7;
        ushort8 v = *reinterpret_cast<const ushort8*>(&qb[(bhS + toks[row]) * 64 + sub * 8]);
        *reinterpret_cast<ushort8*>(&Ks[row][sub * 8]) = v;
    }
    __syncthreads();

    const int lane = tid & 63, w = tid >> 6;
    const int l15 = lane & 15, l4 = lane >> 4;

    f32x4 accd[8];
#pragma unroll
    for (int fn = 0; fn < 8; ++fn) accd[fn] = (f32x4)0.f;
#pragma unroll
    for (int ks = 0; ks < 2; ++ks) {
        bf16x8 a = *reinterpret_cast<const bf16x8*>(&Ks[w * 16 + l15][l4 * 8 + ks * 32]);
#pragma unroll
        for (int fn = 0; fn < 8; ++fn) {
            bf16x8 b = *reinterpret_cast<const bf16x8*>(&Ks[fn * 16 + l15][l4 * 8 + ks * 32]);
            accd[fn] = __builtin_amdgcn_mfma_f32_16x16x32_bf16(a, b, accd[fn], 0, 0, 0);
        }
    }
    __syncthreads();

    float dsum[4] = {0.f, 0.f, 0.f, 0.f};
#pragma unroll
    for (int fn = 0; fn < 8; ++fn) {
        int j = fn * 16 + l15;
        float rj = rk[j];
#pragma unroll
        for (int q = 0; q < 4; ++q) {
            int i = w * 16 + l4 * 4 + q;
            float p = __expf(accd[fn][q] * rj - qn_s[i]);
            dsum[q] += p;
            P[i][j] = f2bf(p);
        }
    }
#pragma unroll
    for (int q = 0; q < 4; ++q) {
#pragma unroll
        for (int off = 1; off < 16; off <<= 1) dsum[q] += __shfl_xor(dsum[q], off);
    }
    if (l15 == 0) {
#pragma unroll
        for (int q = 0; q < 4; ++q)
            D4[gS + toks[w * 16 + l4 * 4 + q]] = dsum[q];    // plain store (exclusive owner)
    }
    // Vt transpose-store, XOR-swizzled: col = row ^ (sub<<3)
#pragma unroll
    for (int i = 0; i < 4; ++i) {
        int cc = tid + 256 * i;
        int row = cc >> 3, sub = cc & 7;
        ushort8 v = *reinterpret_cast<const ushort8*>(&vb[(bhS + toks[row]) * 64 + sub * 8]);
        int colx = row ^ (sub << 3);
#pragma unroll
        for (int e = 0; e < 8; ++e) Vt[sub * 8 + e][colx] = v[e];
    }
    __syncthreads();

    f32x4 acco[4];
#pragma unroll
    for (int fn = 0; fn < 4; ++fn) acco[fn] = (f32x4)0.f;
#pragma unroll
    for (int ks = 0; ks < 4; ++ks) {
        bf16x8 a = *reinterpret_cast<const bf16x8*>(&P[w * 16 + l15][l4 * 8 + ks * 32]);
#pragma unroll
        for (int fn = 0; fn < 4; ++fn) {
            int dh = fn * 16 + l15;
            int key = (dh >> 3) & 7;
            int colr = (l4 * 8 + ks * 32) ^ (key << 3);
            bf16x8 b = *reinterpret_cast<const bf16x8*>(&Vt[dh][colr]);
            acco[fn] = __builtin_amdgcn_mfma_f32_16x16x32_bf16(a, b, acco[fn], 0, 0, 0);
        }
    }
#pragma unroll
    for (int fn = 0; fn < 4; ++fn) {
        int dh = fn * 16 + l15;
#pragma unroll
        for (int q = 0; q < 4; ++q) {
            int i = w * 16 + l4 * 4 + q;
            U4[(gS + toks[i]) * 64 + dh] = f2bf(acco[fn][q]);  // plain store
        }
    }
}

// ---------------------------------------------------------------------------
// Mix v2 (R18-validated): 16-lane-group parallel; sums 4 per-round U/D.
// ---------------------------------------------------------------------------
__global__ __launch_bounds__(256)
void mix_staged(const unsigned short* __restrict__ qb, const float* __restrict__ qnorm,
                const unsigned short* __restrict__ vb,
                const unsigned short* __restrict__ U4, const float* __restrict__ D4,
                const float* __restrict__ w_gate, const float* __restrict__ b_gate,
                unsigned short* __restrict__ mixb, float* __restrict__ gpart) {
    __shared__ unsigned short kq[72][64];
    __shared__ unsigned short vvs[72][64];
    __shared__ float rns[72];
    __shared__ float gacc[4];
    const int tid = threadIdx.x;
    const int bh = blockIdx.y;           // 0..31
    const int s0 = blockIdx.x * 64;
    const int h = bh & 15, b = bh >> 4;
    const size_t bhS = (size_t)bh * S_;

    for (int c = tid; c < 576; c += 256) {          // 72 rows x 8 chunks
        int row = c >> 3, sub = c & 7;
        int idx = s0 - 4 + row;
        int ic = idx < 0 ? 0 : (idx > S_ - 1 ? S_ - 1 : idx);
        *reinterpret_cast<ushort8*>(&kq[row][sub * 8]) =
            *reinterpret_cast<const ushort8*>(&qb[(bhS + ic) * 64 + sub * 8]);
        *reinterpret_cast<ushort8*>(&vvs[row][sub * 8]) =
            *reinterpret_cast<const ushort8*>(&vb[(bhS + ic) * 64 + sub * 8]);
    }
    if (tid < 72) {
        int idx = s0 - 4 + tid;
        int ic = idx < 0 ? 0 : (idx > S_ - 1 ? S_ - 1 : idx);
        rns[tid] = 1.f / (qnorm[bhS + ic] + 1e-6f);
    }
    __syncthreads();

    const int wv = tid >> 6, lane = tid & 63;
    const int grp = lane >> 4, l15 = lane & 15;     // 4 groups of 16 per wave
    const int d0 = l15 * 4;                         // this lane's 4 dh values
    float4 wgl4 = *reinterpret_cast<const float4*>(&w_gate[h * 64 + d0]);
    const float bg = b_gate[h];
    float gsum = 0.f;

#pragma unroll
    for (int t4 = 0; t4 < 4; ++t4) {                // 16 tokens per iteration
        int t = t4 * 16 + wv * 4 + grp;             // unique token in [0,64)
        int s = s0 + t;
        float qd[4];
        {
            ushort4v q4 = *reinterpret_cast<const ushort4v*>(&kq[t + 4][d0]);
#pragma unroll
            for (int e = 0; e < 4; ++e) qd[e] = bf2f(q4[e]);
        }
        float pw[9];
        float4 vbv[9];
#pragma unroll
        for (int wt = 0; wt < 9; ++wt) {
            int idx = s - 4 + wt;
            bool valid = (idx >= 0) && (idx < S_);
            int ic = idx < 0 ? 0 : (idx > S_ - 1 ? S_ - 1 : idx);
            int r = ic - s0 + 4;
            ushort4v k4 = *reinterpret_cast<const ushort4v*>(&kq[r][d0]);
            float p = qd[0] * bf2f(k4[0]) + qd[1] * bf2f(k4[1])
                    + qd[2] * bf2f(k4[2]) + qd[3] * bf2f(k4[3]);
#pragma unroll
            for (int off = 1; off < 16; off <<= 1) p += __shfl_xor(p, off);
            pw[wt] = valid ? p * rns[r] * SCALE_ : -1e9f;
            ushort4v v4 = *reinterpret_cast<const ushort4v*>(&vvs[r][d0]);
            vbv[wt].x = bf2f(v4[0]); vbv[wt].y = bf2f(v4[1]);
            vbv[wt].z = bf2f(v4[2]); vbv[wt].w = bf2f(v4[3]);
        }
        float mx = pw[0];
#pragma unroll
        for (int wt = 1; wt < 9; ++wt) mx = fmaxf(mx, pw[wt]);
        float den = 0.f;
        float4 loc = make_float4(0.f, 0.f, 0.f, 0.f);
#pragma unroll
        for (int wt = 0; wt < 9; ++wt) {
            float e = __expf(pw[wt] - mx);
            den += e;
            loc.x += e * vbv[wt].x; loc.y += e * vbv[wt].y;
            loc.z += e * vbv[wt].z; loc.w += e * vbv[wt].w;
        }
        float rden = 1.f / den;
        loc.x *= rden; loc.y *= rden; loc.z *= rden; loc.w *= rden;

        float gv = qd[0] * wgl4.x + qd[1] * wgl4.y + qd[2] * wgl4.z + qd[3] * wgl4.w;
#pragma unroll
        for (int off = 1; off < 16; off <<= 1) gv += __shfl_xor(gv, off);
        float gg = sigf(gv + bg);

        float un[4] = {0.f, 0.f, 0.f, 0.f};
        float dd = 0.f;
#pragma unroll
        for (int r = 0; r < 4; ++r) {
            size_t grow = ((size_t)(bh * 4 + r) * S_ + s);
            ushort4v u4 = *reinterpret_cast<const ushort4v*>(&U4[grow * 64 + d0]);
#pragma unroll
            for (int e = 0; e < 4; ++e) un[e] += bf2f(u4[e]);
            dd += D4[grow];
        }
        float rdd = 1.f / dd;
        float og = 1.f - gg;
        ushort4v o;
        o[0] = f2bf(gg * loc.x + og * un[0] * rdd);
        o[1] = f2bf(gg * loc.y + og * un[1] * rdd);
        o[2] = f2bf(gg * loc.z + og * un[2] * rdd);
        o[3] = f2bf(gg * loc.w + og * un[3] * rdd);
        *reinterpret_cast<ushort4v*>(&mixb[((size_t)b * S_ + s) * 1024 + h * 64 + d0]) = o;
        if (l15 == 0) gsum += gg * (1.f - gg);
    }
#pragma unroll
    for (int off = 32; off; off >>= 1) gsum += __shfl_xor(gsum, off);
    if (lane == 0) gacc[wv] = gsum;
    __syncthreads();
    if (tid == 0)
        gpart[blockIdx.y * 64 + blockIdx.x] = gacc[0] + gacc[1] + gacc[2] + gacc[3];
}

__global__ __launch_bounds__(256)
void reg_reduce(const float* __restrict__ gpart, float* __restrict__ outreg) {
    __shared__ float part[4];
    float sm = 0.f;
    for (int i = threadIdx.x; i < 2048; i += 256) sm += gpart[i];
#pragma unroll
    for (int off = 32; off; off >>= 1) sm += __shfl_xor(sm, off);
    if ((threadIdx.x & 63) == 0) part[threadIdx.x >> 6] = sm;
    __syncthreads();
    if (threadIdx.x == 0) outreg[0] = (part[0] + part[1] + part[2] + part[3]) * (1.f / 131072.f);
}

// ---------------------------------------------------------------------------
// LayerNorm over D=1024, block per row; bf16 out
// ---------------------------------------------------------------------------
__global__ __launch_bounds__(256)
void ln_kernel(const float* __restrict__ x, const float* __restrict__ gg,
               const float* __restrict__ bb, unsigned short* __restrict__ outp) {
    __shared__ float ps[4][2];
    int row = blockIdx.x, tid = threadIdx.x;
    int wv = tid >> 6, lane = tid & 63;
    const float* xr = x + (size_t)row * 1024;
    float4 xv = *reinterpret_cast<const float4*>(&xr[tid * 4]);
    float s = xv.x + xv.y + xv.z + xv.w;
    float s2 = xv.x * xv.x + xv.y * xv.y + xv.z * xv.z + xv.w * xv.w;
#pragma unroll
    for (int off = 32; off; off >>= 1) { s += __shfl_xor(s, off); s2 += __shfl_xor(s2, off); }
    if (lane == 0) { ps[wv][0] = s; ps[wv][1] = s2; }
    __syncthreads();
    s  = ps[0][0] + ps[1][0] + ps[2][0] + ps[3][0];
    s2 = ps[0][1] + ps[1][1] + ps[2][1] + ps[3][1];
    float mean = s * (1.f / 1024.f);
    float var = s2 * (1.f / 1024.f) - mean * mean;
    float rs = rsqrtf(var + 1e-5f);
    float4 gv = *reinterpret_cast<const float4*>(&gg[tid * 4]);
    float4 bv = *reinterpret_cast<const float4*>(&bb[tid * 4]);
    ushort4v o;
    o[0] = f2bf((xv.x - mean) * rs * gv.x + bv.x);
    o[1] = f2bf((xv.y - mean) * rs * gv.y + bv.y);
    o[2] = f2bf((xv.z - mean) * rs * gv.z + bv.z);
    o[3] = f2bf((xv.w - mean) * rs * gv.w + bv.w);
    *reinterpret_cast<ushort4v*>(&outp[(size_t)row * 1024 + tid * 4]) = o;
}

// ---------------------------------------------------------------------------
// Buffer plan (R22):
//  d_out[0:BSD]   = qk (phase 1) -> U4 lower half -> y1
//  d_out[BSD:2BSD]= x2lo bf16 (phase 1, dead after qk_split) -> U4 upper -> y2
//  ws A 0:        x2b -> qb -> tb      ws B 16777216: vbuf -> hb
//  ws C 33554432: WqkTh/WqkTl -> buckets -> mixb
//  ws D 50331648: WvT (-> D4 after gemm<0>) / WoT / W1T / W2T
//  ws E 58720256: perm    F 60817408: qnorm (0.5MB)
//  61341696: rotTh (0.25MB)   61603840: rotTl (0.25MB)   61865984: gpart
// ---------------------------------------------------------------------------
extern "C" void kernel_launch(void* const* d_in, const int* in_sizes, int n_in,
                              void* d_out, int out_size, void* d_ws, size_t ws_size,
                              hipStream_t stream) {
    (void)in_sizes; (void)n_in; (void)out_size; (void)ws_size;
    const float* x1    = (const float*)d_in[0];
    const float* x2    = (const float*)d_in[1];
    const float* Wqk   = (const float*)d_in[2];
    const float* Wv    = (const float*)d_in[3];
    const float* Wo    = (const float*)d_in[4];
    const float* rot   = (const float*)d_in[5];
    const float* w_gate= (const float*)d_in[6];
    const float* b_gate= (const float*)d_in[7];
    const float* ln_g  = (const float*)d_in[8];
    const float* ln_b  = (const float*)d_in[9];
    const float* W1    = (const float*)d_in[10];
    const float* b1    = (const float*)d_in[11];
    const float* W2    = (const float*)d_in[12];
    const float* b2    = (const float*)d_in[13];
    const float* alpha = (const float*)d_in[14];
    const float* beta  = (const float*)d_in[15];

    float* out = (float*)d_out;
    float* qk  = out;                              // dead after buckets_mfma
    unsigned short* x2lo = (unsigned short*)(out + (size_t)BSD_);  // dead after qk_split
    unsigned short* U4 = (unsigned short*)out;     // 67 MB during attention
    float* y1  = out;
    float* y2  = out + (size_t)BSD_;

    char* ws = (char*)d_ws;
    unsigned short* x2b   = (unsigned short*)(ws + 0);
    unsigned short* qb    = (unsigned short*)(ws + 0);
    unsigned short* tb    = (unsigned short*)(ws + 0);
    unsigned short* vbuf  = (unsigned short*)(ws + 16777216);
    unsigned short* hb    = (unsigned short*)(ws + 16777216);
    unsigned short* WqkTh = (unsigned short*)(ws + 33554432);   // dead before buckets
    unsigned short* WqkTl = (unsigned short*)(ws + 35651584);
    int*   buckets        = (int*)  (ws + 33554432);
    unsigned short* mixb  = (unsigned short*)(ws + 33554432);
    unsigned short* WvT   = (unsigned short*)(ws + 50331648);   // dead after gemm<0>
    float* D4             = (float*) (ws + 50331648);           // 2 MB, reuses WvT slot
    unsigned short* WoT   = (unsigned short*)(ws + 52428800);
    unsigned short* W1T   = (unsigned short*)(ws + 54525952);
    unsigned short* W2T   = (unsigned short*)(ws + 56623104);
    int*   perm           = (int*)  (ws + 58720256);
    float* qnorm          = (float*)(ws + 60817408);
    unsigned short* rotTh = (unsigned short*)(ws + 61341696);   // 0.25 MB
    unsigned short* rotTl = (unsigned short*)(ws + 61603840);   // 0.25 MB
    float* gpart          = (float*)(ws + 61865984);

    dim3 gb(256);
    // x2 -> (hi, lo) bf16; hi == old x2b bit-exactly
    f2bf2_kernel<<<4096, 256, 0, stream>>>(x2, x2b, x2lo);
    wtrans_split<<<dim3(32, 32), 256, 0, stream>>>(Wqk, WqkTh, WqkTl);
    wtrans4<<<dim3(32, 32, 4), 256, 0, stream>>>(Wv, WvT, Wo, WoT, W1, W1T, W2, W2T);
    rott_kernel<<<64, 256, 0, stream>>>(rot, rotTh, rotTl);

    // qk split-GEMM + v GEMM: XCD-chunked 1D grids (512 blocks)
    gemm_qk_split<<<512, gb, 0, stream>>>(x2b, x2lo, WqkTh, WqkTl, qk);
    gemm_bf16<0><<<512, gb, 0, stream>>>(x2b, WvT, vbuf, nullptr, nullptr, nullptr);

    // MFMA buckets (all 4 rounds) + qnorm + qb; 8-wave blocks (R21)
    buckets_mfma<<<dim3(32, 32), 512, 0, stream>>>(qk, rotTh, rotTl, buckets, qb, qnorm);
    sort_kernel<<<128, 256, 0, stream>>>(buckets, perm);

    // atomic-free attention: per-round exclusive plain stores (overwrites qk+x2lo)
    fused_attn<<<8192, 256, 0, stream>>>(qb, vbuf, perm, qnorm, U4, D4);

    mix_staged<<<dim3(64, 32), 256, 0, stream>>>(qb, qnorm, vbuf, U4, D4,
                                                 w_gate, b_gate, mixb, gpart);
    reg_reduce<<<1, 256, 0, stream>>>(gpart, out + 2 * (size_t)BSD_);

    gemm_bf16<1><<<512, gb, 0, stream>>>(mixb, WoT, y1, nullptr, x1, alpha);
    ln_kernel<<<8192, 256, 0, stream>>>(y1, ln_g, ln_b, hb);
    gemm_bf16<2><<<512, gb, 0, stream>>>(hb, W1T, tb, b1, nullptr, nullptr);
    gemm_bf16<3><<<512, gb, 0, stream>>>(tb, W2T, y2, b2, x2, beta);
}